// Round 1
// baseline (208.067 us; speedup 1.0000x reference)
//
#include <hip/hip_runtime.h>
#include <hip/hip_bf16.h>

#define NNODES 50000
#define NEDGES 640000
#define HID 128
#define NWG 500
#define EPW 128   // edges per WG per sweep (4 waves x 32)

typedef __attribute__((ext_vector_type(8)))  short  short8;
typedef __attribute__((ext_vector_type(16))) float  f32x16;
typedef __attribute__((ext_vector_type(4)))  float  f32x4v;

static __device__ __forceinline__ short f2bf(float x) {
    return __builtin_bit_cast(short, __float2bfloat16(x));
}

__global__ __launch_bounds__(256, 2)
void edgehead_mlp(const float* __restrict__ h,
                  const int* __restrict__ ei,
                  const float* __restrict__ ea,
                  const float* __restrict__ W1,
                  const float* __restrict__ b1,
                  const float* __restrict__ W2,
                  const float* __restrict__ b2,
                  float* __restrict__ out)
{
    // W1^T staged as bf16: [col][k] in 16B chunks, chunk index XOR-swizzled by (col&7)
    __shared__ short8 w1t8[128 * 32];   // k = 0..255   (64 KB)
    __shared__ short8 w1e8[128 * 3];    // k = 256..271: [w1[256], w1[257], b1, 0...] (6 KB, 3rd chunk pad)
    short* w1s  = (short*)w1t8;
    short* w1es = (short*)w1e8;

    const int tid = threadIdx.x;

    // ---- stage W1 rows 0..255 (coalesced read, swizzled bf16 write) ----
    for (int idx = tid; idx < 256 * HID; idx += 256) {
        int k = idx >> 7, col = idx & 127;
        w1s[col * 256 + (k ^ ((col & 7) << 3))] = f2bf(W1[idx]);
    }
    // ---- stage ext rows 256..258 (ea0, ea1, bias-row) ----
    if (tid < HID) {
        int col = tid;
        int base = col * 24;
        w1es[base + 0] = f2bf(W1[256 * HID + col]);
        w1es[base + 1] = f2bf(W1[257 * HID + col]);
        w1es[base + 2] = f2bf(b1[col]);
        #pragma unroll
        for (int j = 3; j < 16; ++j) w1es[base + j] = 0;
    }
    __syncthreads();

    const int lane = tid & 63;
    const int wid  = tid >> 6;
    const int l31  = lane & 31;
    const int grp  = lane >> 5;   // 0 or 1

    // runtime dtype hedge for edge_index: int64 read as int32 -> odd slots are zero high-words
    const bool is64 = (ei[1] == 0) && (ei[3] == 0) && (ei[5] == 0) && (ei[7] == 0);
    const long long* ei64 = (const long long*)ei;

    float w2v[4];
    #pragma unroll
    for (int nt = 0; nt < 4; ++nt) w2v[nt] = W2[nt * 32 + l31];
    const float b2v = b2[0];

    for (int ebase = blockIdx.x * EPW + wid * 32; ebase < NEDGES; ebase += NWG * EPW) {
        const int e = ebase + l31;
        const int u = is64 ? (int)ei64[e]          : ei[e];
        const int v = is64 ? (int)ei64[NEDGES + e] : ei[NEDGES + e];
        const float* pu = h + (size_t)u * HID + grp * 8;
        const float* pv = h + (size_t)v * HID + grp * 8;
        const float ea0 = ea[2 * e];
        const float ea1 = ea[2 * e + 1];

        f32x16 acc[4];
        #pragma unroll
        for (int nt = 0; nt < 4; ++nt)
            #pragma unroll
            for (int r = 0; r < 16; ++r) acc[nt][r] = 0.f;

        #pragma unroll
        for (int ks = 0; ks < 17; ++ks) {
            short8 af;
            if (ks < 16) {
                const float* p = (ks < 8) ? (pu + ks * 16) : (pv + (ks - 8) * 16);
                f32x4v a0 = *(const f32x4v*)(p);
                f32x4v a1 = *(const f32x4v*)(p + 4);
                af[0] = f2bf(a0.x); af[1] = f2bf(a0.y);
                af[2] = f2bf(a0.z); af[3] = f2bf(a0.w);
                af[4] = f2bf(a1.x); af[5] = f2bf(a1.y);
                af[6] = f2bf(a1.z); af[7] = f2bf(a1.w);
            } else {
                af[0] = grp ? (short)0 : f2bf(ea0);
                af[1] = grp ? (short)0 : f2bf(ea1);
                af[2] = grp ? (short)0 : (short)0x3F80;  // 1.0bf16 -> picks up b1 row
                af[3] = 0; af[4] = 0; af[5] = 0; af[6] = 0; af[7] = 0;
            }
            #pragma unroll
            for (int nt = 0; nt < 4; ++nt) {
                const int col = nt * 32 + l31;
                short8 bf = (ks < 16)
                    ? w1t8[col * 32 + ((ks * 2 + grp) ^ (l31 & 7))]
                    : w1e8[col * 3 + grp];
                acc[nt] = __builtin_amdgcn_mfma_f32_32x32x16_bf16(af, bf, acc[nt], 0, 0, 0);
            }
        }

        // ---- epilogue: relu * W2, reduce over 128 cols ----
        float pr[16];
        #pragma unroll
        for (int r = 0; r < 16; ++r) {
            float s = fmaxf(acc[0][r], 0.f) * w2v[0];
            s = fmaf(fmaxf(acc[1][r], 0.f), w2v[1], s);
            s = fmaf(fmaxf(acc[2][r], 0.f), w2v[2], s);
            s = fmaf(fmaxf(acc[3][r], 0.f), w2v[3], s);
            pr[r] = s;
        }

        // butterfly fold: 16 regs -> 1 reg across lane bits 0..3 (r_eff = 8*b0+4*b1+2*b2+b3)
        #define FOLD(MASK, A, B) { \
            const bool hi = (lane & MASK) != 0; \
            float snd = hi ? pr[A] : pr[B]; \
            float kp  = hi ? pr[B] : pr[A]; \
            pr[A] = kp + __shfl_xor(snd, MASK, 64); }
        #pragma unroll
        for (int i = 0; i < 8; ++i) FOLD(1, i, i + 8)
        #pragma unroll
        for (int i = 0; i < 4; ++i) FOLD(2, i, i + 4)
        #pragma unroll
        for (int i = 0; i < 2; ++i) FOLD(4, i, i + 2)
        FOLD(8, 0, 1)
        #undef FOLD
        float val = pr[0] + __shfl_xor(pr[0], 16, 64);

        const int reff = ((lane & 1) << 3) | ((lane & 2) << 1) | ((lane & 4) >> 1) | ((lane & 8) >> 3);
        const int row  = (reff & 3) + ((reff >> 2) << 3) + grp * 4;
        if ((lane & 16) == 0) out[ebase + row] = val + b2v;
    }
}

extern "C" void kernel_launch(void* const* d_in, const int* in_sizes, int n_in,
                              void* d_out, int out_size, void* d_ws, size_t ws_size,
                              hipStream_t stream) {
    const float* h  = (const float*)d_in[0];
    const int*   ei = (const int*)d_in[1];
    const float* ea = (const float*)d_in[2];
    const float* W1 = (const float*)d_in[3];
    const float* b1 = (const float*)d_in[4];
    const float* W2 = (const float*)d_in[5];
    const float* b2 = (const float*)d_in[6];
    float* out = (float*)d_out;
    hipLaunchKernelGGL(edgehead_mlp, dim3(NWG), dim3(256), 0, stream,
                       h, ei, ea, W1, b1, W2, b2, out);
}